// Round 7
// baseline (166.026 us; speedup 1.0000x reference)
//
#include <hip/hip_runtime.h>
#include <hip/hip_bf16.h>

// HyperbolicMessagePassing: N=50000, E=600000, D=128.
// out = expmap0( MLP2( mean_scatter( MLP1(logmap0(x))[src] -> dst ) ) )
// Message MLP depends only on src -> compute per-node (50k rows not 600k).
// R16 = R14 fused structure + per-XCD-replicated CSR fill:
//   R15 split showed fill ~= 35-40us of stage1's 44.5 (atomic wall). Theory:
//   cross-XCD line-ownership migration on 600k random-line atomicAdds.
//   Replicate degv/ebuf 8x keyed by blockIdx&7 (round-robin block->XCD):
//   each replica's lines are touched by ONE XCD -> L2-local RMW, no
//   migration. Stage2 gathers 8 short lists/row (2 half-batches of 4
//   regions x 4-slot windows + rare tails); mean = sum / (total count).

#define DD 128
#define CAP8 16  // padded-CSR slots per node per XCD replica (Poisson(1.5))
#define NR 8     // replicas

typedef __attribute__((ext_vector_type(8))) short short8;
typedef __attribute__((ext_vector_type(8))) unsigned short u16x8;
typedef __attribute__((ext_vector_type(4))) unsigned short u16x4;
typedef __attribute__((ext_vector_type(4))) float f32x4;

__device__ __forceinline__ unsigned short f2bf(float f) {
  unsigned u = __float_as_uint(f);
  u += 0x7fffu + ((u >> 16) & 1u);  // round-to-nearest-even
  return (unsigned short)(u >> 16);
}
__device__ __forceinline__ float bf2f(short h) {
  return __uint_as_float(((unsigned)(unsigned short)h) << 16);
}

// blocks [0,32): pack 4 W (fp32 128x128) into bf16 MFMA B-frag-linear order:
//   P[m*16384 + ((cc*4+s)*64 + lane)*8 + j]
//     = bf16(W[(s*32+(lane>>4)*8+j)*128 + cc*16+(lane&15)])
// blocks [32,..): zero degv8[NR*N]
__global__ void k_init(const float* __restrict__ w1, const float* __restrict__ w2,
                       const float* __restrict__ w3, const float* __restrict__ w4,
                       unsigned short* __restrict__ P, int* __restrict__ degv8, int N) {
  if (blockIdx.x < 32) {
    int idx = blockIdx.x * 256 + threadIdx.x;  // 4 matrices x 2048 (frag,lane)
    int m = idx >> 11;
    int id = idx & 2047;
    int f = id >> 6, l = id & 63;
    int cc = f >> 2, s = f & 3, q = l >> 4, n15 = l & 15;
    const float* W = (m == 0) ? w1 : (m == 1) ? w2 : (m == 2) ? w3 : w4;
    const float* wp = W + (s * 32 + q * 8) * DD + cc * 16 + n15;
    unsigned short* op = P + (size_t)m * 16384 + (size_t)id * 8;
#pragma unroll
    for (int j = 0; j < 8; ++j) op[j] = f2bf(wp[j * DD]);
  } else {
    int i = (blockIdx.x - 32) * 256 + threadIdx.x;
    if (i < NR * N) degv8[i] = 0;
  }
}

// stage1: blocks [0,ne) = replicated edge fill, 4 edges/thread (dispatched
//         FIRST, overlaps MLP); blocks [ne,..) = logmap0 + MLP1 -> node_msg.
// 256 threads = 4 waves. Wave wv: rt=wv>>1 (16 rows), ct=wv&1 (64 cols).
__global__ __launch_bounds__(256) void k_stage1(
    const float* __restrict__ x, const int* __restrict__ ei,
    const unsigned short* __restrict__ Pa, const float* __restrict__ ba,
    const unsigned short* __restrict__ Pb, const float* __restrict__ bb,
    unsigned short* __restrict__ node_msg, int* __restrict__ degv8,
    unsigned short* __restrict__ ebuf8, int N, int E, int ne) {
  __shared__ unsigned short As[32 * 136];  // row stride 136 shorts
  const int tid = threadIdx.x;

  if (blockIdx.x < ne) {  // ---- edge-fill: 1024 edges/block, 4/thread ----
    const int rg = blockIdx.x & (NR - 1);  // replica = this block's XCD
    int eb_[4], d_[4], s_[4], p_[4];
#pragma unroll
    for (int k = 0; k < 4; ++k) {
      int e = blockIdx.x * 1024 + k * 256 + tid;
      eb_[k] = e;
      if (e < E) {
        d_[k] = ei[e];       // edge_index[0] = dst
        s_[k] = ei[E + e];   // edge_index[1] = src
      }
    }
#pragma unroll
    for (int k = 0; k < 4; ++k)
      if (eb_[k] < E)
        p_[k] = atomicAdd(degv8 + (size_t)rg * N + d_[k], 1);
#pragma unroll
    for (int k = 0; k < 4; ++k)
      if (eb_[k] < E && p_[k] < CAP8)
        ebuf8[((size_t)rg * N + d_[k]) * CAP8 + p_[k]] = (unsigned short)s_[k];
    return;
  }

  const int lane = tid & 63;
  const int wv = tid >> 6;  // 0..3
  const int rt = wv >> 1;   // row-tile 0..1
  const int ct = wv & 1;    // col-tile 0..1
  const int q = lane >> 4;
  const int n15 = lane & 15;
  const int row0 = (blockIdx.x - ne) * 32;
  const int g = (wv << 2) | q;  // staging group 0..15

  // ---- stage A tile: logmap0, group g rows g*2..g*2+1, 16 lanes/row ----
  f32x4 xa[2][2];
#pragma unroll
  for (int i = 0; i < 2; ++i) {
    const int grow = row0 + g * 2 + i;
    if (grow < N) {
      const f32x4* p = (const f32x4*)(x + (size_t)grow * DD + n15 * 8);
      xa[i][0] = p[0];
      xa[i][1] = p[1];
    } else {
      xa[i][0] = (f32x4){0.f, 0.f, 0.f, 0.f};
      xa[i][1] = (f32x4){0.f, 0.f, 0.f, 0.f};
    }
  }
#pragma unroll
  for (int i = 0; i < 2; ++i) {
    const int r = g * 2 + i;
    f32x4 s0 = xa[i][0], s1 = xa[i][1];
    float ss = s0[0]*s0[0] + s0[1]*s0[1] + s0[2]*s0[2] + s0[3]*s0[3]
             + s1[0]*s1[0] + s1[1]*s1[1] + s1[2]*s1[2] + s1[3]*s1[3];
    ss += __shfl_xor(ss, 1);
    ss += __shfl_xor(ss, 2);
    ss += __shfl_xor(ss, 4);
    ss += __shfl_xor(ss, 8);
    float nrm = sqrtf(ss);
    float nc = fminf(fmaxf(nrm, 1e-8f), 1.0f - 1e-5f);
    float sc = atanhf(nc) / nc;
    s0 *= sc;
    s1 *= sc;
    uint4 pk;
    pk.x = (unsigned)f2bf(s0[0]) | ((unsigned)f2bf(s0[1]) << 16);
    pk.y = (unsigned)f2bf(s0[2]) | ((unsigned)f2bf(s0[3]) << 16);
    pk.z = (unsigned)f2bf(s1[0]) | ((unsigned)f2bf(s1[1]) << 16);
    pk.w = (unsigned)f2bf(s1[2]) | ((unsigned)f2bf(s1[3]) << 16);
    *(uint4*)((unsigned*)As + r * 68 + n15 * 4) = pk;
  }
  __syncthreads();

  // ---- layer 1 ----
  float bc[4];
#pragma unroll
  for (int c = 0; c < 4; ++c) bc[c] = ba[ct * 64 + c * 16 + n15];
  f32x4 acc[4];
#pragma unroll
  for (int c = 0; c < 4; ++c) acc[c] = (f32x4){0.f, 0.f, 0.f, 0.f};
  const int abase = (rt * 16 + n15) * 136 + q * 8;  // A[m=n15][k=q*8+j]
  short8 bfr[16];
#pragma unroll
  for (int s = 0; s < 4; ++s)
#pragma unroll
    for (int c = 0; c < 4; ++c)
      bfr[s * 4 + c] =
          *(const short8*)&Pa[(size_t)(((((ct << 2) | c) << 2) | s) * 64 + lane) * 8];
  short8 afr[4];
#pragma unroll
  for (int s = 0; s < 4; ++s) afr[s] = *(const short8*)&As[abase + s * 32];
#pragma unroll
  for (int s = 0; s < 4; ++s)
#pragma unroll
    for (int c = 0; c < 4; ++c)
      acc[c] = __builtin_amdgcn_mfma_f32_16x16x32_bf16(afr[s], bfr[s * 4 + c],
                                                       acc[c], 0, 0, 0);
  __syncthreads();

  // relu + bias -> As (C/D: row = rt*16 + q*4 + rr, col = ct*64 + c*16 + n15)
#pragma unroll
  for (int c = 0; c < 4; ++c)
#pragma unroll
    for (int rr = 0; rr < 4; ++rr) {
      float v = fmaxf(acc[c][rr] + bc[c], 0.f);
      As[(rt * 16 + q * 4 + rr) * 136 + ct * 64 + c * 16 + n15] = f2bf(v);
    }
  __syncthreads();

  // ---- layer 2 ----
#pragma unroll
  for (int c = 0; c < 4; ++c) bc[c] = bb[ct * 64 + c * 16 + n15];
#pragma unroll
  for (int c = 0; c < 4; ++c) acc[c] = (f32x4){0.f, 0.f, 0.f, 0.f};
#pragma unroll
  for (int s = 0; s < 4; ++s)
#pragma unroll
    for (int c = 0; c < 4; ++c)
      bfr[s * 4 + c] =
          *(const short8*)&Pb[(size_t)(((((ct << 2) | c) << 2) | s) * 64 + lane) * 8];
#pragma unroll
  for (int s = 0; s < 4; ++s) afr[s] = *(const short8*)&As[abase + s * 32];
#pragma unroll
  for (int s = 0; s < 4; ++s)
#pragma unroll
    for (int c = 0; c < 4; ++c)
      acc[c] = __builtin_amdgcn_mfma_f32_16x16x32_bf16(afr[s], bfr[s * 4 + c],
                                                       acc[c], 0, 0, 0);

  // write bf16 node_msg via LDS repack -> coalesced 16B stores
  __syncthreads();
#pragma unroll
  for (int c = 0; c < 4; ++c)
#pragma unroll
    for (int rr = 0; rr < 4; ++rr)
      As[(rt * 16 + q * 4 + rr) * 136 + ct * 64 + c * 16 + n15] =
          f2bf(acc[c][rr] + bc[c]);
  __syncthreads();
#pragma unroll
  for (int k = 0; k < 2; ++k) {  // 32 rows x 16 chunks = 512 units / 256 thr
    int u = tid + k * 256;
    int r = u >> 4, ch = u & 15;
    int grow = row0 + r;
    if (grow < N)
      *(short8*)(node_msg + (size_t)grow * DD + ch * 8) =
          *(const short8*)&As[r * 136 + ch * 8];
  }
}

// stage2: replicated-CSR gather + mean -> 2-layer MLP -> expmap0 -> out (f32)
__global__ __launch_bounds__(256) void k_stage2(
    const unsigned short* __restrict__ node_msg, const int* __restrict__ degv8,
    const unsigned short* __restrict__ ebuf8, const unsigned short* __restrict__ Pa,
    const float* __restrict__ ba, const unsigned short* __restrict__ Pb,
    const float* __restrict__ bb, float* __restrict__ out, int N) {
  __shared__ unsigned short As[32 * 136];
  __shared__ float nrmb[64];  // [row][ct] partial norms
  const int tid = threadIdx.x;
  const int lane = tid & 63;
  const int wv = tid >> 6;  // 0..3
  const int rt = wv >> 1;
  const int ct = wv & 1;
  const int q = lane >> 4;
  const int n15 = lane & 15;
  const int row0 = blockIdx.x * 32;
  const int g = (wv << 2) | q;  // 0..15

  // ---- gather + mean across 8 replicas ----
#pragma unroll
  for (int i = 0; i < 2; ++i) {
    const int r = g * 2 + i;
    const int grow = row0 + r;
    f32x4 s0 = {0.f, 0.f, 0.f, 0.f}, s1 = {0.f, 0.f, 0.f, 0.f};
    f32x4 t0 = {0.f, 0.f, 0.f, 0.f}, t1 = {0.f, 0.f, 0.f, 0.f};
    int dtot = 0;
    if (grow < N) {
      // hoist all replica counts + 4-slot index windows (16 loads in flight)
      int d8[NR];
#pragma unroll
      for (int rg = 0; rg < NR; ++rg) d8[rg] = degv8[(size_t)rg * N + grow];
      u16x4 cw[NR];
#pragma unroll
      for (int rg = 0; rg < NR; ++rg)
        cw[rg] = *(const u16x4*)(ebuf8 + ((size_t)rg * N + grow) * CAP8);
#pragma unroll
      for (int rg = 0; rg < NR; ++rg) dtot += d8[rg];

      // two half-batches: regions [0,4) then [4,8), 16 gathers per batch
#pragma unroll
      for (int h = 0; h < 2; ++h) {
        short8 v[16];
#pragma unroll
        for (int rr8 = 0; rr8 < 4; ++rr8)
#pragma unroll
          for (int t = 0; t < 4; ++t) {
            const int rg = h * 4 + rr8;
            int sidx = (t < d8[rg]) ? (int)cw[rg][t] : 0;  // poison -> row 0
            v[rr8 * 4 + t] =
                *(const short8*)(node_msg + (size_t)sidx * DD + n15 * 8);
          }
#pragma unroll
        for (int rr8 = 0; rr8 < 4; ++rr8)
#pragma unroll
          for (int t = 0; t < 4; ++t) {
            const int rg = h * 4 + rr8;
            if (t < d8[rg]) {
              const short8 vv = v[rr8 * 4 + t];
#pragma unroll
              for (int j = 0; j < 4; ++j) {
                if (t & 1) {
                  t0[j] += bf2f(vv[j]);
                  t1[j] += bf2f(vv[j + 4]);
                } else {
                  s0[j] += bf2f(vv[j]);
                  s1[j] += bf2f(vv[j + 4]);
                }
              }
            }
          }
      }
      // rare tails: replica count > 4 (Poisson(1.5) tail)
#pragma unroll
      for (int rg = 0; rg < NR; ++rg) {
        int dl = (d8[rg] < CAP8) ? d8[rg] : CAP8;
        if (dl > 4) {
          const unsigned short* eb = ebuf8 + ((size_t)rg * N + grow) * CAP8;
          for (int t = 4; t < dl; ++t) {
            int sa = eb[t];
            short8 va = *(const short8*)(node_msg + (size_t)sa * DD + n15 * 8);
#pragma unroll
            for (int j = 0; j < 4; ++j) {
              s0[j] += bf2f(va[j]);
              s1[j] += bf2f(va[j + 4]);
            }
          }
        }
      }
      s0 += t0;
      s1 += t1;
      float inv = 1.f / ((float)dtot + 1e-8f);  // mean (count + EPS)
      s0 *= inv;
      s1 *= inv;
    }
    uint4 pk;
    pk.x = (unsigned)f2bf(s0[0]) | ((unsigned)f2bf(s0[1]) << 16);
    pk.y = (unsigned)f2bf(s0[2]) | ((unsigned)f2bf(s0[3]) << 16);
    pk.z = (unsigned)f2bf(s1[0]) | ((unsigned)f2bf(s1[1]) << 16);
    pk.w = (unsigned)f2bf(s1[2]) | ((unsigned)f2bf(s1[3]) << 16);
    *(uint4*)((unsigned*)As + r * 68 + n15 * 4) = pk;
  }
  __syncthreads();

  // ---- layer 1 ----
  float bc[4];
#pragma unroll
  for (int c = 0; c < 4; ++c) bc[c] = ba[ct * 64 + c * 16 + n15];
  f32x4 acc[4];
#pragma unroll
  for (int c = 0; c < 4; ++c) acc[c] = (f32x4){0.f, 0.f, 0.f, 0.f};
  const int abase = (rt * 16 + n15) * 136 + q * 8;
  short8 bfr[16];
#pragma unroll
  for (int s = 0; s < 4; ++s)
#pragma unroll
    for (int c = 0; c < 4; ++c)
      bfr[s * 4 + c] =
          *(const short8*)&Pa[(size_t)(((((ct << 2) | c) << 2) | s) * 64 + lane) * 8];
  short8 afr[4];
#pragma unroll
  for (int s = 0; s < 4; ++s) afr[s] = *(const short8*)&As[abase + s * 32];
#pragma unroll
  for (int s = 0; s < 4; ++s)
#pragma unroll
    for (int c = 0; c < 4; ++c)
      acc[c] = __builtin_amdgcn_mfma_f32_16x16x32_bf16(afr[s], bfr[s * 4 + c],
                                                       acc[c], 0, 0, 0);
  __syncthreads();

#pragma unroll
  for (int c = 0; c < 4; ++c)
#pragma unroll
    for (int rr = 0; rr < 4; ++rr) {
      float v = fmaxf(acc[c][rr] + bc[c], 0.f);
      As[(rt * 16 + q * 4 + rr) * 136 + ct * 64 + c * 16 + n15] = f2bf(v);
    }
  __syncthreads();

  // ---- layer 2 ----
#pragma unroll
  for (int c = 0; c < 4; ++c) bc[c] = bb[ct * 64 + c * 16 + n15];
#pragma unroll
  for (int c = 0; c < 4; ++c) acc[c] = (f32x4){0.f, 0.f, 0.f, 0.f};
#pragma unroll
  for (int s = 0; s < 4; ++s)
#pragma unroll
    for (int c = 0; c < 4; ++c)
      bfr[s * 4 + c] =
          *(const short8*)&Pb[(size_t)(((((ct << 2) | c) << 2) | s) * 64 + lane) * 8];
#pragma unroll
  for (int s = 0; s < 4; ++s) afr[s] = *(const short8*)&As[abase + s * 32];
#pragma unroll
  for (int s = 0; s < 4; ++s)
#pragma unroll
    for (int c = 0; c < 4; ++c)
      acc[c] = __builtin_amdgcn_mfma_f32_16x16x32_bf16(afr[s], bfr[s * 4 + c],
                                                       acc[c], 0, 0, 0);

  // ---- expmap0 epilogue ----
  float v[4][4];
#pragma unroll
  for (int rr = 0; rr < 4; ++rr) {
    float ssq = 0.f;
#pragma unroll
    for (int c = 0; c < 4; ++c) {
      v[c][rr] = acc[c][rr] + bc[c];
      ssq += v[c][rr] * v[c][rr];
    }
    ssq += __shfl_xor(ssq, 1);
    ssq += __shfl_xor(ssq, 2);
    ssq += __shfl_xor(ssq, 4);
    ssq += __shfl_xor(ssq, 8);
    if (n15 == 0) nrmb[(rt * 16 + q * 4 + rr) * 2 + ct] = ssq;
  }
  __syncthreads();
#pragma unroll
  for (int rr = 0; rr < 4; ++rr) {
    int r = rt * 16 + q * 4 + rr;
    int grow = row0 + r;
    float ssq = nrmb[r * 2] + nrmb[r * 2 + 1];
    float nrm = sqrtf(ssq);
    float nc = fmaxf(nrm, 1e-8f);
    float sc = tanhf(nc) / nc;
    if (grow < N) {
#pragma unroll
      for (int c = 0; c < 4; ++c)
        __builtin_nontemporal_store(
            v[c][rr] * sc, out + (size_t)grow * DD + ct * 64 + c * 16 + n15);
    }
  }
}

extern "C" void kernel_launch(void* const* d_in, const int* in_sizes, int n_in,
                              void* d_out, int out_size, void* d_ws, size_t ws_size,
                              hipStream_t stream) {
  const float* x = (const float*)d_in[0];
  const int* ei = (const int*)d_in[1];
  const float* w1 = (const float*)d_in[2];
  const float* b1 = (const float*)d_in[3];
  const float* w2 = (const float*)d_in[4];
  const float* b2 = (const float*)d_in[5];
  const float* w3 = (const float*)d_in[6];
  const float* b3 = (const float*)d_in[7];
  const float* w4 = (const float*)d_in[8];
  const float* b4 = (const float*)d_in[9];
  const int N = in_sizes[0] / DD;
  const int E = in_sizes[1] / 2;
  const int nf = (N + 31) / 32;
  const int ne = (E + 1023) / 1024;  // 4 edges/thread, 1024/block

  // ws carve: node_msg[N*128 bf16] | degv8[8N int] | ebuf8[8N*CAP8 u16] |
  //           P[4*16384 bf16]   (~27.5 MB total)
  unsigned short* node_msg = (unsigned short*)d_ws;
  int* degv8 = (int*)(node_msg + (size_t)N * DD);
  unsigned short* ebuf8 = (unsigned short*)(degv8 + (size_t)NR * N);
  uintptr_t pw = (uintptr_t)(ebuf8 + (size_t)NR * N * CAP8);
  pw = (pw + 63) & ~(uintptr_t)63;
  unsigned short* P = (unsigned short*)pw;
  float* outp = (float*)d_out;

  hipLaunchKernelGGL(k_init, dim3(32 + (NR * N + 255) / 256), dim3(256), 0,
                     stream, w1, w2, w3, w4, P, degv8, N);
  hipLaunchKernelGGL(k_stage1, dim3(ne + nf), dim3(256), 0, stream,
                     x, ei, P, b1, P + 16384, b2, node_msg, degv8, ebuf8, N, E, ne);
  hipLaunchKernelGGL(k_stage2, dim3(nf), dim3(256), 0, stream,
                     node_msg, degv8, ebuf8, P + 2 * 16384, b3, P + 3 * 16384, b4,
                     outp, N);
}

// Round 8
// 155.567 us; speedup vs baseline: 1.0672x; 1.0672x over previous
//
#include <hip/hip_runtime.h>
#include <hip/hip_bf16.h>

// HyperbolicMessagePassing: N=50000, E=600000, D=128.
// out = expmap0( MLP2( mean_scatter( MLP1(logmap0(x))[src] -> dst ) ) )
// Message MLP depends only on src -> compute per-node (50k rows not 600k).
// R17 = R14 base (158.2us best: fused fill+MLP stage1, DS-padded degv,
// u16 ebuf CAP=64) + barrier-convoy-free stage2:
//   R16 counters showed stage2 at 21% occupancy, nothing saturated: the
//   4-wave block convoys at __syncthreads (slowest gather gates MFMA).
//   New stage2: 1 wave / 16 rows / block (grid 3125), gather + full
//   128-col MFMA + expmap0 all within one wave; no inter-wave barriers,
//   no nrmb LDS; degree variance no longer convoys.

#define DD 128
#define CAP 64   // padded-CSR slots per node
#define DS 16    // degv stride in ints (64B line per counter)

typedef __attribute__((ext_vector_type(8))) short short8;
typedef __attribute__((ext_vector_type(8))) unsigned short u16x8;
typedef __attribute__((ext_vector_type(4))) unsigned short u16x4;
typedef __attribute__((ext_vector_type(4))) float f32x4;

__device__ __forceinline__ unsigned short f2bf(float f) {
  unsigned u = __float_as_uint(f);
  u += 0x7fffu + ((u >> 16) & 1u);  // round-to-nearest-even
  return (unsigned short)(u >> 16);
}
__device__ __forceinline__ float bf2f(short h) {
  return __uint_as_float(((unsigned)(unsigned short)h) << 16);
}

// blocks [0,32): pack 4 W (fp32 128x128) into bf16 MFMA B-frag-linear order:
//   P[m*16384 + ((cc*4+s)*64 + lane)*8 + j]
//     = bf16(W[(s*32+(lane>>4)*8+j)*128 + cc*16+(lane&15)])
// blocks [32,..): zero degv[N] (padded stride DS)
__global__ void k_init(const float* __restrict__ w1, const float* __restrict__ w2,
                       const float* __restrict__ w3, const float* __restrict__ w4,
                       unsigned short* __restrict__ P, int* __restrict__ degv, int N) {
  if (blockIdx.x < 32) {
    int idx = blockIdx.x * 256 + threadIdx.x;  // 4 matrices x 2048 (frag,lane)
    int m = idx >> 11;
    int id = idx & 2047;
    int f = id >> 6, l = id & 63;
    int cc = f >> 2, s = f & 3, q = l >> 4, n15 = l & 15;
    const float* W = (m == 0) ? w1 : (m == 1) ? w2 : (m == 2) ? w3 : w4;
    const float* wp = W + (s * 32 + q * 8) * DD + cc * 16 + n15;
    unsigned short* op = P + (size_t)m * 16384 + (size_t)id * 8;
#pragma unroll
    for (int j = 0; j < 8; ++j) op[j] = f2bf(wp[j * DD]);
  } else {
    int i = (blockIdx.x - 32) * 256 + threadIdx.x;
    if (i < N) degv[(size_t)i * DS] = 0;
  }
}

// stage1: blocks [0,ne) = padded-CSR edge fill, 4 edges/thread (dispatched
//         FIRST, overlaps MLP); blocks [ne,..) = logmap0 + MLP1 -> node_msg.
// 256 threads = 4 waves. Wave wv: rt=wv>>1 (16 rows), ct=wv&1 (64 cols).
__global__ __launch_bounds__(256) void k_stage1(
    const float* __restrict__ x, const int* __restrict__ ei,
    const unsigned short* __restrict__ Pa, const float* __restrict__ ba,
    const unsigned short* __restrict__ Pb, const float* __restrict__ bb,
    unsigned short* __restrict__ node_msg, int* __restrict__ degv,
    unsigned short* __restrict__ ebuf, int N, int E, int ne) {
  __shared__ unsigned short As[32 * 136];  // row stride 136 shorts
  const int tid = threadIdx.x;

  if (blockIdx.x < ne) {  // ---- edge-fill: 1024 edges/block, 4/thread ----
    int eb_[4], d_[4], s_[4], p_[4];
#pragma unroll
    for (int k = 0; k < 4; ++k) {
      int e = blockIdx.x * 1024 + k * 256 + tid;
      eb_[k] = e;
      if (e < E) {
        d_[k] = ei[e];       // edge_index[0] = dst
        s_[k] = ei[E + e];   // edge_index[1] = src
      }
    }
#pragma unroll
    for (int k = 0; k < 4; ++k)
      if (eb_[k] < E) p_[k] = atomicAdd(degv + (size_t)d_[k] * DS, 1);
#pragma unroll
    for (int k = 0; k < 4; ++k)
      if (eb_[k] < E && p_[k] < CAP)
        ebuf[(size_t)d_[k] * CAP + p_[k]] = (unsigned short)s_[k];
    return;
  }

  const int lane = tid & 63;
  const int wv = tid >> 6;  // 0..3
  const int rt = wv >> 1;   // row-tile 0..1
  const int ct = wv & 1;    // col-tile 0..1
  const int q = lane >> 4;
  const int n15 = lane & 15;
  const int row0 = (blockIdx.x - ne) * 32;
  const int g = (wv << 2) | q;  // staging group 0..15

  // ---- stage A tile: logmap0, group g rows g*2..g*2+1, 16 lanes/row ----
  f32x4 xa[2][2];
#pragma unroll
  for (int i = 0; i < 2; ++i) {
    const int grow = row0 + g * 2 + i;
    if (grow < N) {
      const f32x4* p = (const f32x4*)(x + (size_t)grow * DD + n15 * 8);
      xa[i][0] = p[0];
      xa[i][1] = p[1];
    } else {
      xa[i][0] = (f32x4){0.f, 0.f, 0.f, 0.f};
      xa[i][1] = (f32x4){0.f, 0.f, 0.f, 0.f};
    }
  }
#pragma unroll
  for (int i = 0; i < 2; ++i) {
    const int r = g * 2 + i;
    f32x4 s0 = xa[i][0], s1 = xa[i][1];
    float ss = s0[0]*s0[0] + s0[1]*s0[1] + s0[2]*s0[2] + s0[3]*s0[3]
             + s1[0]*s1[0] + s1[1]*s1[1] + s1[2]*s1[2] + s1[3]*s1[3];
    ss += __shfl_xor(ss, 1);
    ss += __shfl_xor(ss, 2);
    ss += __shfl_xor(ss, 4);
    ss += __shfl_xor(ss, 8);
    float nrm = sqrtf(ss);
    float nc = fminf(fmaxf(nrm, 1e-8f), 1.0f - 1e-5f);
    float sc = atanhf(nc) / nc;
    s0 *= sc;
    s1 *= sc;
    uint4 pk;
    pk.x = (unsigned)f2bf(s0[0]) | ((unsigned)f2bf(s0[1]) << 16);
    pk.y = (unsigned)f2bf(s0[2]) | ((unsigned)f2bf(s0[3]) << 16);
    pk.z = (unsigned)f2bf(s1[0]) | ((unsigned)f2bf(s1[1]) << 16);
    pk.w = (unsigned)f2bf(s1[2]) | ((unsigned)f2bf(s1[3]) << 16);
    *(uint4*)((unsigned*)As + r * 68 + n15 * 4) = pk;
  }
  __syncthreads();

  // ---- layer 1 ----
  float bc[4];
#pragma unroll
  for (int c = 0; c < 4; ++c) bc[c] = ba[ct * 64 + c * 16 + n15];
  f32x4 acc[4];
#pragma unroll
  for (int c = 0; c < 4; ++c) acc[c] = (f32x4){0.f, 0.f, 0.f, 0.f};
  const int abase = (rt * 16 + n15) * 136 + q * 8;  // A[m=n15][k=q*8+j]
  short8 bfr[16];
#pragma unroll
  for (int s = 0; s < 4; ++s)
#pragma unroll
    for (int c = 0; c < 4; ++c)
      bfr[s * 4 + c] =
          *(const short8*)&Pa[(size_t)(((((ct << 2) | c) << 2) | s) * 64 + lane) * 8];
  short8 afr[4];
#pragma unroll
  for (int s = 0; s < 4; ++s) afr[s] = *(const short8*)&As[abase + s * 32];
#pragma unroll
  for (int s = 0; s < 4; ++s)
#pragma unroll
    for (int c = 0; c < 4; ++c)
      acc[c] = __builtin_amdgcn_mfma_f32_16x16x32_bf16(afr[s], bfr[s * 4 + c],
                                                       acc[c], 0, 0, 0);
  __syncthreads();

  // relu + bias -> As (C/D: row = rt*16 + q*4 + rr, col = ct*64 + c*16 + n15)
#pragma unroll
  for (int c = 0; c < 4; ++c)
#pragma unroll
    for (int rr = 0; rr < 4; ++rr) {
      float v = fmaxf(acc[c][rr] + bc[c], 0.f);
      As[(rt * 16 + q * 4 + rr) * 136 + ct * 64 + c * 16 + n15] = f2bf(v);
    }
  __syncthreads();

  // ---- layer 2 ----
#pragma unroll
  for (int c = 0; c < 4; ++c) bc[c] = bb[ct * 64 + c * 16 + n15];
#pragma unroll
  for (int c = 0; c < 4; ++c) acc[c] = (f32x4){0.f, 0.f, 0.f, 0.f};
#pragma unroll
  for (int s = 0; s < 4; ++s)
#pragma unroll
    for (int c = 0; c < 4; ++c)
      bfr[s * 4 + c] =
          *(const short8*)&Pb[(size_t)(((((ct << 2) | c) << 2) | s) * 64 + lane) * 8];
#pragma unroll
  for (int s = 0; s < 4; ++s) afr[s] = *(const short8*)&As[abase + s * 32];
#pragma unroll
  for (int s = 0; s < 4; ++s)
#pragma unroll
    for (int c = 0; c < 4; ++c)
      acc[c] = __builtin_amdgcn_mfma_f32_16x16x32_bf16(afr[s], bfr[s * 4 + c],
                                                       acc[c], 0, 0, 0);

  // write bf16 node_msg via LDS repack -> coalesced 16B stores
  __syncthreads();
#pragma unroll
  for (int c = 0; c < 4; ++c)
#pragma unroll
    for (int rr = 0; rr < 4; ++rr)
      As[(rt * 16 + q * 4 + rr) * 136 + ct * 64 + c * 16 + n15] =
          f2bf(acc[c][rr] + bc[c]);
  __syncthreads();
#pragma unroll
  for (int k = 0; k < 2; ++k) {  // 32 rows x 16 chunks = 512 units / 256 thr
    int u = tid + k * 256;
    int r = u >> 4, ch = u & 15;
    int grow = row0 + r;
    if (grow < N)
      *(short8*)(node_msg + (size_t)grow * DD + ch * 8) =
          *(const short8*)&As[r * 136 + ch * 8];
  }
}

// stage2: 1 wave / 16 rows / block. Gather + mean -> MLP2 -> expmap0 -> out.
// lane: q=lane>>4 (group, rows q*4..q*4+3), n15=lane&15 (cols n15*8..+8).
__global__ __launch_bounds__(64) void k_stage2(
    const unsigned short* __restrict__ node_msg, const int* __restrict__ degv,
    const unsigned short* __restrict__ ebuf, const unsigned short* __restrict__ Pa,
    const float* __restrict__ ba, const unsigned short* __restrict__ Pb,
    const float* __restrict__ bb, float* __restrict__ out, int N) {
  __shared__ unsigned short As[16 * 136];
  const int lane = threadIdx.x;  // 0..63
  const int q = lane >> 4;
  const int n15 = lane & 15;
  const int row0 = blockIdx.x * 16;

  // ---- gather + mean: group q handles rows q*4..q*4+3, 16-slot window ----
#pragma unroll
  for (int i = 0; i < 4; ++i) {
    const int r = q * 4 + i;
    const int grow = row0 + r;
    f32x4 s0 = {0.f, 0.f, 0.f, 0.f}, s1 = {0.f, 0.f, 0.f, 0.f};
    if (grow < N) {
      const int d = degv[(size_t)grow * DS];
      const int dl = (d < CAP) ? d : CAP;
      const unsigned short* eb = ebuf + (size_t)grow * CAP;
      u16x8 cA = *(const u16x8*)(eb);
      u16x8 cB = *(const u16x8*)(eb + 8);
      int id[16];
#pragma unroll
      for (int t = 0; t < 8; ++t) {
        id[t] = cA[t];
        id[t + 8] = cB[t];
      }
      short8 v[16];
#pragma unroll
      for (int t = 0; t < 16; ++t) {
        int sidx = (t < dl) ? id[t] : 0;  // clamp poison to a safe hot row
        v[t] = *(const short8*)(node_msg + (size_t)sidx * DD + n15 * 8);
      }
      f32x4 t0 = {0.f, 0.f, 0.f, 0.f}, t1 = {0.f, 0.f, 0.f, 0.f};
#pragma unroll
      for (int t = 0; t < 16; ++t) {
        if (t < dl) {
#pragma unroll
          for (int j = 0; j < 4; ++j) {
            if (t & 1) {
              t0[j] += bf2f(v[t][j]);
              t1[j] += bf2f(v[t][j + 4]);
            } else {
              s0[j] += bf2f(v[t][j]);
              s1[j] += bf2f(v[t][j + 4]);
            }
          }
        }
      }
      // tail: deg > 16 (~10% of rows), 4-deep
      int t = 16;
      for (; t + 3 < dl; t += 4) {
        u16x4 idx = *(const u16x4*)(eb + t);
        short8 v0 = *(const short8*)(node_msg + (size_t)idx[0] * DD + n15 * 8);
        short8 v1 = *(const short8*)(node_msg + (size_t)idx[1] * DD + n15 * 8);
        short8 v2 = *(const short8*)(node_msg + (size_t)idx[2] * DD + n15 * 8);
        short8 v3 = *(const short8*)(node_msg + (size_t)idx[3] * DD + n15 * 8);
#pragma unroll
        for (int j = 0; j < 4; ++j) {
          s0[j] += bf2f(v0[j]) + bf2f(v1[j]);
          s1[j] += bf2f(v0[j + 4]) + bf2f(v1[j + 4]);
          t0[j] += bf2f(v2[j]) + bf2f(v3[j]);
          t1[j] += bf2f(v2[j + 4]) + bf2f(v3[j + 4]);
        }
      }
      for (; t < dl; ++t) {
        int sa = eb[t];
        short8 va = *(const short8*)(node_msg + (size_t)sa * DD + n15 * 8);
#pragma unroll
        for (int j = 0; j < 4; ++j) {
          s0[j] += bf2f(va[j]);
          s1[j] += bf2f(va[j + 4]);
        }
      }
      s0 += t0;
      s1 += t1;
      float inv = 1.f / ((float)d + 1e-8f);  // mean (count + EPS)
      s0 *= inv;
      s1 *= inv;
    }
    uint4 pk;
    pk.x = (unsigned)f2bf(s0[0]) | ((unsigned)f2bf(s0[1]) << 16);
    pk.y = (unsigned)f2bf(s0[2]) | ((unsigned)f2bf(s0[3]) << 16);
    pk.z = (unsigned)f2bf(s1[0]) | ((unsigned)f2bf(s1[1]) << 16);
    pk.w = (unsigned)f2bf(s1[2]) | ((unsigned)f2bf(s1[3]) << 16);
    *(uint4*)((unsigned*)As + r * 68 + n15 * 4) = pk;
  }
  __syncthreads();  // single wave: cheap s_barrier + waitcnt

  // ---- layer 1: 16 rows x 128 cols in one wave (8 col-frags) ----
  float bc[8];
#pragma unroll
  for (int cc = 0; cc < 8; ++cc) bc[cc] = ba[cc * 16 + n15];
  f32x4 acc[8];
#pragma unroll
  for (int cc = 0; cc < 8; ++cc) acc[cc] = (f32x4){0.f, 0.f, 0.f, 0.f};
  const int abase = n15 * 136 + q * 8;  // A[row=n15][k=q*8+j]
  short8 afr[4];
#pragma unroll
  for (int s = 0; s < 4; ++s) afr[s] = *(const short8*)&As[abase + s * 32];
#pragma unroll
  for (int s = 0; s < 4; ++s)
#pragma unroll
    for (int cc = 0; cc < 8; ++cc) {
      short8 b = *(const short8*)&Pa[(size_t)((cc * 4 + s) * 64 + lane) * 8];
      acc[cc] = __builtin_amdgcn_mfma_f32_16x16x32_bf16(afr[s], b, acc[cc], 0, 0, 0);
    }
  __syncthreads();

  // relu + bias -> As (C/D: row = q*4 + rr, col = cc*16 + n15)
#pragma unroll
  for (int cc = 0; cc < 8; ++cc)
#pragma unroll
    for (int rr = 0; rr < 4; ++rr) {
      float v = fmaxf(acc[cc][rr] + bc[cc], 0.f);
      As[(q * 4 + rr) * 136 + cc * 16 + n15] = f2bf(v);
    }
  __syncthreads();

  // ---- layer 2 ----
#pragma unroll
  for (int cc = 0; cc < 8; ++cc) bc[cc] = bb[cc * 16 + n15];
#pragma unroll
  for (int cc = 0; cc < 8; ++cc) acc[cc] = (f32x4){0.f, 0.f, 0.f, 0.f};
#pragma unroll
  for (int s = 0; s < 4; ++s) afr[s] = *(const short8*)&As[abase + s * 32];
#pragma unroll
  for (int s = 0; s < 4; ++s)
#pragma unroll
    for (int cc = 0; cc < 8; ++cc) {
      short8 b = *(const short8*)&Pb[(size_t)((cc * 4 + s) * 64 + lane) * 8];
      acc[cc] = __builtin_amdgcn_mfma_f32_16x16x32_bf16(afr[s], b, acc[cc], 0, 0, 0);
    }

  // ---- expmap0 epilogue: row q*4+rr fully within this 16-lane group ----
#pragma unroll
  for (int rr = 0; rr < 4; ++rr) {
    float vv[8];
    float ssq = 0.f;
#pragma unroll
    for (int cc = 0; cc < 8; ++cc) {
      vv[cc] = acc[cc][rr] + bc[cc];
      ssq += vv[cc] * vv[cc];
    }
    ssq += __shfl_xor(ssq, 1);
    ssq += __shfl_xor(ssq, 2);
    ssq += __shfl_xor(ssq, 4);
    ssq += __shfl_xor(ssq, 8);
    float nrm = sqrtf(ssq);
    float nc = fmaxf(nrm, 1e-8f);
    float sc = tanhf(nc) / nc;
    int grow = row0 + q * 4 + rr;
    if (grow < N) {
#pragma unroll
      for (int cc = 0; cc < 8; ++cc)
        __builtin_nontemporal_store(
            vv[cc] * sc, out + (size_t)grow * DD + cc * 16 + n15);
    }
  }
}

extern "C" void kernel_launch(void* const* d_in, const int* in_sizes, int n_in,
                              void* d_out, int out_size, void* d_ws, size_t ws_size,
                              hipStream_t stream) {
  const float* x = (const float*)d_in[0];
  const int* ei = (const int*)d_in[1];
  const float* w1 = (const float*)d_in[2];
  const float* b1 = (const float*)d_in[3];
  const float* w2 = (const float*)d_in[4];
  const float* b2 = (const float*)d_in[5];
  const float* w3 = (const float*)d_in[6];
  const float* b3 = (const float*)d_in[7];
  const float* w4 = (const float*)d_in[8];
  const float* b4 = (const float*)d_in[9];
  const int N = in_sizes[0] / DD;
  const int E = in_sizes[1] / 2;
  const int nf = (N + 31) / 32;
  const int nf2 = (N + 15) / 16;
  const int ne = (E + 1023) / 1024;  // 4 edges/thread, 1024/block

  // ws carve: node_msg[N*128 bf16] | degv[N*16 int, 64B-padded] |
  //           ebuf[N*64 u16] | P[4*16384 bf16]   (~22.5 MB total)
  unsigned short* node_msg = (unsigned short*)d_ws;
  int* degv = (int*)(node_msg + (size_t)N * DD);
  unsigned short* ebuf = (unsigned short*)(degv + (size_t)N * DS);
  uintptr_t pw = (uintptr_t)(ebuf + (size_t)N * CAP);
  pw = (pw + 63) & ~(uintptr_t)63;
  unsigned short* P = (unsigned short*)pw;
  float* outp = (float*)d_out;

  hipLaunchKernelGGL(k_init, dim3(32 + (N + 255) / 256), dim3(256), 0, stream,
                     w1, w2, w3, w4, P, degv, N);
  hipLaunchKernelGGL(k_stage1, dim3(ne + nf), dim3(256), 0, stream,
                     x, ei, P, b1, P + 16384, b2, node_msg, degv, ebuf, N, E, ne);
  hipLaunchKernelGGL(k_stage2, dim3(nf2), dim3(64), 0, stream,
                     node_msg, degv, ebuf, P + 2 * 16384, b3, P + 3 * 16384, b4,
                     outp, N);
}